// Round 1
// baseline (655.015 us; speedup 1.0000x reference)
//
#include <hip/hip_runtime.h>
#include <math.h>

#define BB 16
#define TT 128
#define VV 32000
#define HH 768
#define PP 384
#define NBOWD 64
#define EPS_LS 0.05f
#define TAUC 0.07f

__device__ __forceinline__ float blockReduceSum256(float v, float* sh) {
  int tid = threadIdx.x;
  sh[tid] = v;
  __syncthreads();
  for (int s = 128; s > 0; s >>= 1) {
    if (tid < s) sh[tid] += sh[tid + s];
    __syncthreads();
  }
  float r = sh[0];
  __syncthreads();
  return r;
}

// ---------------- CE: one-pass online softmax stats per token row ----------------
__global__ __launch_bounds__(256) void ce_kernel(const float* __restrict__ logits,
                                                 const int* __restrict__ labels,
                                                 float* __restrict__ tok,
                                                 float* __restrict__ vfs) {
  int row = blockIdx.x;  // 0..B*T-1
  const float* x = logits + (size_t)row * VV;
  const float4* x4 = (const float4*)x;
  int tid = threadIdx.x;
  float m = -INFINITY, s = 0.f, sx = 0.f;
  for (int k = tid; k < VV / 4; k += 256) {
    float4 v = x4[k];
    float lm = fmaxf(fmaxf(v.x, v.y), fmaxf(v.z, v.w));
    float ls = __expf(v.x - lm) + __expf(v.y - lm) + __expf(v.z - lm) + __expf(v.w - lm);
    sx += (v.x + v.y) + (v.z + v.w);
    float nm = fmaxf(m, lm);
    s = s * __expf(m - nm) + ls * __expf(lm - nm);
    m = nm;
  }
  __shared__ float sm_[256], ss_[256], sxa[256];
  sm_[tid] = m; ss_[tid] = s; sxa[tid] = sx;
  __syncthreads();
  for (int o = 128; o > 0; o >>= 1) {
    if (tid < o) {
      float m2 = sm_[tid + o], s2 = ss_[tid + o];
      float nm = fmaxf(sm_[tid], m2);
      ss_[tid] = ss_[tid] * __expf(sm_[tid] - nm) + s2 * __expf(m2 - nm);
      sm_[tid] = nm;
      sxa[tid] += sxa[tid + o];
    }
    __syncthreads();
  }
  if (tid == 0) {
    float M = sm_[0], L = logf(ss_[0]), SX = sxa[0];
    int lab = labels[row];
    bool valid = (lab != 0) && (lab != -100);
    int lc = lab < 0 ? 0 : (lab > VV - 1 ? VV - 1 : lab);
    float xl = x[lc];
    float lp_lab = xl - M - L;
    float lp_sum = SX - (float)VV * (M + L);
    float tl = -((1.f - EPS_LS) * lp_lab + (EPS_LS / (float)VV) * lp_sum);
    tok[row] = valid ? tl : 0.f;
    vfs[row] = valid ? 1.f : 0.f;
  }
}

// ---------------- projection head: blocks 0..15 encoder path, 16..31 pooled path ----------------
__global__ __launch_bounds__(256) void proj_kernel(
    const float* __restrict__ enc, const float* __restrict__ dh, const int* __restrict__ amask,
    const float* __restrict__ g_e, const float* __restrict__ be_, const float* __restrict__ W1e,
    const float* __restrict__ b1e, const float* __restrict__ W2e, const float* __restrict__ b2e,
    const float* __restrict__ g_t, const float* __restrict__ bt_, const float* __restrict__ W1t,
    const float* __restrict__ b1t, const float* __restrict__ W2t, const float* __restrict__ b2t,
    float* __restrict__ ze, float* __restrict__ zt) {
  __shared__ float xs[HH];
  __shared__ float hs[PP];
  __shared__ float red[256];
  __shared__ float mf[TT];
  __shared__ float mdenom;
  int tid = threadIdx.x;
  int blk = blockIdx.x;
  bool is_t = blk >= BB;
  int b = blk & (BB - 1);
  const float *g, *bb_, *W1, *b1, *W2, *b2;
  float* zout;
  if (is_t) { g = g_t; bb_ = bt_; W1 = W1t; b1 = b1t; W2 = W2t; b2 = b2t; zout = zt; }
  else      { g = g_e; bb_ = be_; W1 = W1e; b1 = b1e; W2 = W2e; b2 = b2e; zout = ze; }

  if (is_t) {
    if (tid < TT) mf[tid] = (float)amask[b * TT + tid];
    __syncthreads();
    if (tid == 0) {
      float s = 0.f;
      for (int t = 0; t < TT; t++) s += mf[t];
      mdenom = fmaxf(s, 1.f);
    }
    __syncthreads();
    const float* dbase = dh + (size_t)b * TT * HH;
    for (int h = tid; h < HH; h += 256) {
      float acc = 0.f;
      for (int t = 0; t < TT; t++) acc += dbase[t * HH + h] * mf[t];
      xs[h] = acc / mdenom;
    }
  } else {
    for (int k = tid; k < HH; k += 256) xs[k] = enc[b * HH + k];
  }
  __syncthreads();

  // LayerNorm (biased var, eps 1e-5)
  float s1 = 0.f, s2 = 0.f;
  for (int k = tid; k < HH; k += 256) { float v = xs[k]; s1 += v; s2 += v * v; }
  s1 = blockReduceSum256(s1, red);
  s2 = blockReduceSum256(s2, red);
  float mean = s1 / (float)HH;
  float var = s2 / (float)HH - mean * mean;
  float rstd = rsqrtf(var + 1e-5f);
  for (int k = tid; k < HH; k += 256) xs[k] = (xs[k] - mean) * rstd * g[k] + bb_[k];
  __syncthreads();

  // h1 = gelu_exact(xn @ W1 + b1)
  for (int j = tid; j < PP; j += 256) {
    float acc = b1[j];
    for (int k = 0; k < HH; k++) acc += xs[k] * W1[k * PP + j];
    hs[j] = 0.5f * acc * (1.f + erff(acc * 0.70710678118654752440f));
  }
  __syncthreads();
  // z = h1 @ W2 + b2  (store into xs[0..PP))
  for (int j = tid; j < PP; j += 256) {
    float acc = b2[j];
    for (int k = 0; k < PP; k++) acc += hs[k] * W2[k * PP + j];
    xs[j] = acc;
  }
  __syncthreads();
  float sq = 0.f;
  for (int j = tid; j < PP; j += 256) { float v = xs[j]; sq += v * v; }
  sq = blockReduceSum256(sq, red);
  float inv = 1.f / fmaxf(sqrtf(sq), 1e-12f);
  for (int j = tid; j < PP; j += 256) zout[b * PP + j] = xs[j] * inv;
}

// ---------------- finalize: CE reduce + InfoNCE + BoW BCE + diversity + variance ----------------
__global__ __launch_bounds__(256) void finalize_kernel(
    const float* __restrict__ tok, const float* __restrict__ vfs,
    const float* __restrict__ ze, const float* __restrict__ zt,
    const float* __restrict__ enc, const int* __restrict__ labels,
    const float* __restrict__ W_bow, const float* __restrict__ b_bow,
    float* __restrict__ out) {
  __shared__ float sh[256];
  __shared__ float smat[256];
  __shared__ float misc[40];
  int tid = threadIdx.x;

  // CE reduce
  float tsum = 0.f, csum = 0.f;
  for (int i = tid; i < BB * TT; i += 256) { tsum += tok[i]; csum += vfs[i]; }
  float ce_sum = blockReduceSum256(tsum, sh);
  float ce_cnt = blockReduceSum256(csum, sh);

  // sim = (z_e @ z_t^T)/tau ; 256 threads = 256 entries
  {
    int i = tid >> 4, j = tid & 15;
    const float* a = ze + i * PP;
    const float* c = zt + j * PP;
    float d = 0.f;
    for (int k = 0; k < PP; k++) d += a[k] * c[k];
    smat[tid] = d * (1.f / TAUC);
  }
  __syncthreads();
  if (tid < 32) {
    bool isrow = tid < 16;
    int r = tid & 15;
    float mx = -1e30f;
    for (int j = 0; j < 16; j++) { float v = isrow ? smat[r * 16 + j] : smat[j * 16 + r]; mx = fmaxf(mx, v); }
    float se = 0.f;
    for (int j = 0; j < 16; j++) { float v = isrow ? smat[r * 16 + j] : smat[j * 16 + r]; se += __expf(v - mx); }
    misc[tid] = smat[r * 17] - mx - logf(se);   // diag log-softmax (row or col)
  }
  __syncthreads();
  if (tid == 0) {
    float li = 0.f, lj = 0.f;
    for (int r = 0; r < 16; r++) { li += misc[r]; lj += misc[16 + r]; }
    misc[32] = 0.5f * (-(li / 16.f) - (lj / 16.f));
  }
  __syncthreads();
  float align = misc[32];

  // BoW BCE
  float bsum = 0.f;
  for (int e = tid; e < BB * NBOWD; e += 256) {
    int b = e >> 6, iw = e & 63;
    float bl = b_bow[iw];
    const float* er = enc + b * HH;
    for (int k = 0; k < HH; k++) bl += er[k] * W_bow[k * NBOWD + iw];
    int tgt = 0;
    for (int t = 0; t < TT; t++) {
      int lab = labels[b * TT + t];
      if (lab != 0 && lab != -100) {
        int lc = lab < 0 ? 0 : (lab > VV - 1 ? VV - 1 : lab);
        if (lc == iw * 500) tgt = 1;
      }
    }
    bsum += fmaxf(bl, 0.f) - bl * (float)tgt + log1pf(__expf(-fabsf(bl)));
  }
  float bce = blockReduceSum256(bsum, sh) / (float)(BB * NBOWD);

  // diversity: Gram matrix of encoder rows
  __syncthreads();
  {
    int i = tid >> 4, j = tid & 15;
    const float* a = enc + i * HH;
    const float* c = enc + j * HH;
    float d = 0.f;
    for (int k = 0; k < HH; k++) d += a[k] * c[k];
    smat[tid] = d;
  }
  __syncthreads();
  float contrib = 0.f;
  {
    int i = tid >> 4, j = tid & 15;
    if (i != j) {
      float ni = fmaxf(sqrtf(smat[i * 17]), 1e-12f);
      float nj = fmaxf(sqrtf(smat[j * 17]), 1e-12f);
      contrib = fabsf(smat[tid]) / (ni * nj);
    }
  }
  float divs = blockReduceSum256(contrib, sh) / (float)(BB * BB - BB);

  // variance regularizer (ddof=1)
  float vsum = 0.f;
  for (int d = tid; d < HH; d += 256) {
    float a1 = 0.f, a2 = 0.f;
    for (int b = 0; b < BB; b++) { float v = enc[b * HH + d]; a1 += v; a2 += v * v; }
    float mean = a1 / (float)BB;
    float vr = (a2 - (float)BB * mean * mean) / (float)(BB - 1);
    vsum += __expf(-vr);
  }
  float varl = blockReduceSum256(vsum, sh) / (float)HH;

  if (tid == 0) {
    float ce = ce_sum / fmaxf(ce_cnt, 1.f);
    out[0] = 1.0f * ce + 0.5f * align + 0.2f * bce + 0.1f * divs + 0.05f * varl;
  }
}

extern "C" void kernel_launch(void* const* d_in, const int* in_sizes, int n_in,
                              void* d_out, int out_size, void* d_ws, size_t ws_size,
                              hipStream_t stream) {
  const float* logits = (const float*)d_in[0];
  const int* labels   = (const int*)d_in[1];
  const int* amask    = (const int*)d_in[2];
  const float* enc    = (const float*)d_in[3];
  const float* dh     = (const float*)d_in[4];
  const float* g_e    = (const float*)d_in[5];
  const float* be_    = (const float*)d_in[6];
  const float* W1e    = (const float*)d_in[7];
  const float* b1e    = (const float*)d_in[8];
  const float* W2e    = (const float*)d_in[9];
  const float* b2e    = (const float*)d_in[10];
  const float* g_t    = (const float*)d_in[11];
  const float* bt_    = (const float*)d_in[12];
  const float* W1t    = (const float*)d_in[13];
  const float* b1t    = (const float*)d_in[14];
  const float* W2t    = (const float*)d_in[15];
  const float* b2t    = (const float*)d_in[16];
  const float* W_bow  = (const float*)d_in[17];
  const float* b_bow  = (const float*)d_in[18];

  float* f  = (float*)d_ws;
  float* tok = f;                // B*T = 2048
  float* vfs = f + 2048;         // 2048
  float* ze  = f + 4096;         // 16*384
  float* zt  = f + 4096 + 6144;  // 16*384

  ce_kernel<<<BB * TT, 256, 0, stream>>>(logits, labels, tok, vfs);
  proj_kernel<<<2 * BB, 256, 0, stream>>>(enc, dh, amask, g_e, be_, W1e, b1e, W2e, b2e,
                                          g_t, bt_, W1t, b1t, W2t, b2t, ze, zt);
  finalize_kernel<<<1, 256, 0, stream>>>(tok, vfs, ze, zt, enc, labels, W_bow, b_bow, (float*)d_out);
}

// Round 2
// 505.666 us; speedup vs baseline: 1.2953x; 1.2953x over previous
//
#include <hip/hip_runtime.h>
#include <math.h>

#define BB 16
#define TT 128
#define VV 32000
#define HH 768
#define PP 384
#define NBOWD 64
#define EPS_LS 0.05f
#define TAUC 0.07f
#define SMALLB 50   // blocks 0..15 proj-e, 16..31 proj-t, 32..47 bow, 48 div, 49 var

__device__ __forceinline__ float blockReduceSum256(float v, float* sh) {
  int tid = threadIdx.x;
  sh[tid] = v;
  __syncthreads();
  for (int s = 128; s > 0; s >>= 1) {
    if (tid < s) sh[tid] += sh[tid + s];
    __syncthreads();
  }
  float r = sh[0];
  __syncthreads();
  return r;
}

// One dispatch: CE rows (2048 blocks) + all small latency-bound tasks (50 blocks,
// scheduled first so they hide under the CE memory stream).
__global__ __launch_bounds__(256) void fused_main(
    const float* __restrict__ logits, const int* __restrict__ labels, const int* __restrict__ amask,
    const float* __restrict__ enc, const float* __restrict__ dh,
    const float* __restrict__ g_e, const float* __restrict__ be_, const float* __restrict__ W1e,
    const float* __restrict__ b1e, const float* __restrict__ W2e, const float* __restrict__ b2e,
    const float* __restrict__ g_t, const float* __restrict__ bt_, const float* __restrict__ W1t,
    const float* __restrict__ b1t, const float* __restrict__ W2t, const float* __restrict__ b2t,
    const float* __restrict__ W_bow, const float* __restrict__ b_bow,
    float* __restrict__ tok, float* __restrict__ vfs,
    float* __restrict__ ze, float* __restrict__ zt,
    float* __restrict__ bce_p, float* __restrict__ div_p, float* __restrict__ var_p) {
  __shared__ float smem[1792];
  int tid = threadIdx.x;
  int blk = blockIdx.x;

  if (blk >= SMALLB) {
    // ---------------- CE: one-pass online softmax stats per token row ----------------
    int row = blk - SMALLB;
    const float* x = logits + (size_t)row * VV;
    const float4* x4 = (const float4*)x;
    float m = -INFINITY, s = 0.f, sx = 0.f;
    for (int k = tid; k < VV / 4; k += 256) {
      float4 v = x4[k];
      float lm = fmaxf(fmaxf(v.x, v.y), fmaxf(v.z, v.w));
      float ls = __expf(v.x - lm) + __expf(v.y - lm) + __expf(v.z - lm) + __expf(v.w - lm);
      sx += (v.x + v.y) + (v.z + v.w);
      float nm = fmaxf(m, lm);
      s = s * __expf(m - nm) + ls * __expf(lm - nm);
      m = nm;
    }
    float* sm_ = smem;
    float* ss_ = smem + 256;
    float* sxa = smem + 512;
    sm_[tid] = m; ss_[tid] = s; sxa[tid] = sx;
    __syncthreads();
    for (int o = 128; o > 0; o >>= 1) {
      if (tid < o) {
        float m2 = sm_[tid + o], s2 = ss_[tid + o];
        float nm = fmaxf(sm_[tid], m2);
        ss_[tid] = ss_[tid] * __expf(sm_[tid] - nm) + s2 * __expf(m2 - nm);
        sm_[tid] = nm;
        sxa[tid] += sxa[tid + o];
      }
      __syncthreads();
    }
    if (tid == 0) {
      float M = sm_[0], L = logf(ss_[0]), SX = sxa[0];
      int lab = labels[row];
      bool valid = (lab != 0) && (lab != -100);
      int lc = lab < 0 ? 0 : (lab > VV - 1 ? VV - 1 : lab);
      float xl = x[lc];
      float lp_lab = xl - M - L;
      float lp_sum = SX - (float)VV * (M + L);
      float tl = -((1.f - EPS_LS) * lp_lab + (EPS_LS / (float)VV) * lp_sum);
      tok[row] = valid ? tl : 0.f;
      vfs[row] = valid ? 1.f : 0.f;
    }
    return;
  }

  if (blk < 32) {
    // ---------------- projection heads ----------------
    float* xs = smem;          // HH
    float* hs = smem + 768;    // PP
    float* red = smem + 1152;  // 256
    float* mf = smem + 1408;   // TT
    float* mden = smem + 1536; // 1
    bool is_t = blk >= BB;
    int b = blk & (BB - 1);
    const float *g, *bb_, *W1, *b1, *W2, *b2;
    float* zout;
    if (is_t) { g = g_t; bb_ = bt_; W1 = W1t; b1 = b1t; W2 = W2t; b2 = b2t; zout = zt; }
    else      { g = g_e; bb_ = be_; W1 = W1e; b1 = b1e; W2 = W2e; b2 = b2e; zout = ze; }

    if (is_t) {
      if (tid < TT) mf[tid] = (float)amask[b * TT + tid];
      __syncthreads();
      if (tid == 0) {
        float sum = 0.f;
        for (int t = 0; t < TT; t++) sum += mf[t];
        mden[0] = fmaxf(sum, 1.f);
      }
      __syncthreads();
      const float* dbase = dh + (size_t)b * TT * HH;
      for (int h = tid; h < HH; h += 256) {
        float acc = 0.f;
        for (int t = 0; t < TT; t++) acc += dbase[t * HH + h] * mf[t];
        xs[h] = acc / mden[0];
      }
    } else {
      for (int k = tid; k < HH; k += 256) xs[k] = enc[b * HH + k];
    }
    __syncthreads();

    float s1 = 0.f, s2 = 0.f;
    for (int k = tid; k < HH; k += 256) { float v = xs[k]; s1 += v; s2 += v * v; }
    s1 = blockReduceSum256(s1, red);
    s2 = blockReduceSum256(s2, red);
    float mean = s1 / (float)HH;
    float var = s2 / (float)HH - mean * mean;
    float rstd = rsqrtf(var + 1e-5f);
    for (int k = tid; k < HH; k += 256) xs[k] = (xs[k] - mean) * rstd * g[k] + bb_[k];
    __syncthreads();

    for (int j = tid; j < PP; j += 256) {
      float acc = b1[j];
      for (int k = 0; k < HH; k++) acc += xs[k] * W1[k * PP + j];
      hs[j] = 0.5f * acc * (1.f + erff(acc * 0.70710678118654752440f));
    }
    __syncthreads();
    for (int j = tid; j < PP; j += 256) {
      float acc = b2[j];
      for (int k = 0; k < PP; k++) acc += hs[k] * W2[k * PP + j];
      red[0]; // no-op
      xs[j] = acc;  // safe: xs[0..PP) consumed already
    }
    __syncthreads();
    float sq = 0.f;
    for (int j = tid; j < PP; j += 256) { float v = xs[j]; sq += v * v; }
    sq = blockReduceSum256(sq, red);
    float inv = 1.f / fmaxf(sqrtf(sq), 1e-12f);
    for (int j = tid; j < PP; j += 256) zout[b * PP + j] = xs[j] * inv;
    return;
  }

  if (blk < 48) {
    // ---------------- BoW logits + targets for one batch row ----------------
    int b = blk - 32;
    int iw = tid & 63, p = tid >> 6;  // p in 0..3 splits K
    int* labs = (int*)(smem + 512);
    if (tid < TT) labs[tid] = labels[b * TT + tid];
    const float* er = enc + b * HH;
    float acc = 0.f;
    for (int k = p * 192; k < (p + 1) * 192; k++) acc += er[k] * W_bow[k * NBOWD + iw];
    smem[p * 64 + iw] = acc;
    __syncthreads();
    if (tid < 64) {
      float bl = b_bow[iw] + smem[iw] + smem[64 + iw] + smem[128 + iw] + smem[192 + iw];
      int target = 0, idv = iw * 500;
      for (int t = 0; t < TT; t++) {
        int lab = labs[t];
        if (lab != 0 && lab != -100) {
          int lc = lab < 0 ? 0 : (lab > VV - 1 ? VV - 1 : lab);
          if (lc == idv) target = 1;
        }
      }
      smem[256 + iw] = fmaxf(bl, 0.f) - bl * (float)target + log1pf(__expf(-fabsf(bl)));
    }
    __syncthreads();
    if (tid == 0) {
      float s = 0.f;
      for (int i = 0; i < 64; i++) s += smem[256 + i];
      bce_p[b] = s;
    }
    return;
  }

  if (blk == 48) {
    // ---------------- diversity: Gram of encoder rows ----------------
    int i = tid >> 4, j = tid & 15;
    const float* a = enc + i * HH;
    const float* c = enc + j * HH;
    float d = 0.f;
    for (int k = 0; k < HH; k++) d += a[k] * c[k];
    smem[tid] = d;
    __syncthreads();
    float contrib = 0.f;
    if (i != j) {
      float ni = fmaxf(sqrtf(smem[i * 17]), 1e-12f);
      float nj = fmaxf(sqrtf(smem[j * 17]), 1e-12f);
      contrib = fabsf(smem[tid]) / (ni * nj);
    }
    float r = blockReduceSum256(contrib, smem + 256);
    if (tid == 0) div_p[0] = r / (float)(BB * BB - BB);
    return;
  }

  {
    // ---------------- variance regularizer (ddof=1) ----------------
    float vsum = 0.f;
    for (int d = tid; d < HH; d += 256) {
      float a1 = 0.f, a2 = 0.f;
      for (int b = 0; b < BB; b++) { float v = enc[b * HH + d]; a1 += v; a2 += v * v; }
      float mean = a1 / (float)BB;
      float vr = (a2 - (float)BB * mean * mean) / (float)(BB - 1);
      vsum += __expf(-vr);
    }
    float r = blockReduceSum256(vsum, smem);
    if (tid == 0) var_p[0] = r / (float)HH;
  }
}

// ---------------- tiny epilogue: reduces + InfoNCE + combine ----------------
__global__ __launch_bounds__(256) void finalize2(
    const float* __restrict__ tok, const float* __restrict__ vfs,
    const float* __restrict__ ze, const float* __restrict__ zt,
    const float* __restrict__ bce_p, const float* __restrict__ div_p, const float* __restrict__ var_p,
    float* __restrict__ out) {
  __shared__ float sh[256];
  __shared__ float smat[256];
  __shared__ float misc[40];
  int tid = threadIdx.x;

  float tsum = 0.f, csum = 0.f;
  for (int i = tid; i < BB * TT; i += 256) { tsum += tok[i]; csum += vfs[i]; }
  float ce_sum = blockReduceSum256(tsum, sh);
  float ce_cnt = blockReduceSum256(csum, sh);

  {
    int i = tid >> 4, j = tid & 15;
    const float* a = ze + i * PP;
    const float* c = zt + j * PP;
    float d = 0.f;
    for (int k = 0; k < PP; k++) d += a[k] * c[k];
    smat[tid] = d * (1.f / TAUC);
  }
  __syncthreads();
  if (tid < 32) {
    bool isrow = tid < 16;
    int r = tid & 15;
    float mx = -1e30f;
    for (int j = 0; j < 16; j++) { float v = isrow ? smat[r * 16 + j] : smat[j * 16 + r]; mx = fmaxf(mx, v); }
    float se = 0.f;
    for (int j = 0; j < 16; j++) { float v = isrow ? smat[r * 16 + j] : smat[j * 16 + r]; se += __expf(v - mx); }
    misc[tid] = smat[r * 17] - mx - logf(se);
  }
  __syncthreads();
  if (tid == 0) {
    float li = 0.f, lj = 0.f;
    for (int r = 0; r < 16; r++) { li += misc[r]; lj += misc[16 + r]; }
    float align = 0.5f * (-(li / 16.f) - (lj / 16.f));
    float bce = 0.f;
    for (int b = 0; b < BB; b++) bce += bce_p[b];
    bce /= (float)(BB * NBOWD);
    float ce = ce_sum / fmaxf(ce_cnt, 1.f);
    out[0] = 1.0f * ce + 0.5f * align + 0.2f * bce + 0.1f * div_p[0] + 0.05f * var_p[0];
  }
}

extern "C" void kernel_launch(void* const* d_in, const int* in_sizes, int n_in,
                              void* d_out, int out_size, void* d_ws, size_t ws_size,
                              hipStream_t stream) {
  const float* logits = (const float*)d_in[0];
  const int* labels   = (const int*)d_in[1];
  const int* amask    = (const int*)d_in[2];
  const float* enc    = (const float*)d_in[3];
  const float* dh     = (const float*)d_in[4];
  const float* g_e    = (const float*)d_in[5];
  const float* be_    = (const float*)d_in[6];
  const float* W1e    = (const float*)d_in[7];
  const float* b1e    = (const float*)d_in[8];
  const float* W2e    = (const float*)d_in[9];
  const float* b2e    = (const float*)d_in[10];
  const float* g_t    = (const float*)d_in[11];
  const float* bt_    = (const float*)d_in[12];
  const float* W1t    = (const float*)d_in[13];
  const float* b1t    = (const float*)d_in[14];
  const float* W2t    = (const float*)d_in[15];
  const float* b2t    = (const float*)d_in[16];
  const float* W_bow  = (const float*)d_in[17];
  const float* b_bow  = (const float*)d_in[18];

  float* f   = (float*)d_ws;
  float* tok = f;                 // 2048
  float* vfs = f + 2048;          // 2048
  float* ze  = f + 4096;          // 6144
  float* zt  = f + 10240;         // 6144
  float* bce_p = f + 16384;       // 16
  float* div_p = f + 16400;       // 1
  float* var_p = f + 16401;       // 1

  fused_main<<<SMALLB + BB * TT, 256, 0, stream>>>(
      logits, labels, amask, enc, dh,
      g_e, be_, W1e, b1e, W2e, b2e,
      g_t, bt_, W1t, b1t, W2t, b2t,
      W_bow, b_bow, tok, vfs, ze, zt, bce_p, div_p, var_p);
  finalize2<<<1, 256, 0, stream>>>(tok, vfs, ze, zt, bce_p, div_p, var_p, (float*)d_out);
}

// Round 3
// 474.458 us; speedup vs baseline: 1.3806x; 1.0658x over previous
//
#include <hip/hip_runtime.h>
#include <math.h>

#define BB 16
#define TT 128
#define VV 32000
#define HH 768
#define PP 384
#define NBOWD 64
#define EPS_LS 0.05f
#define TAUC 0.07f
// small blocks: 0..31 proj, 32..95 bow(b*4+kq), 96..99 div(kq), 100 var
#define SMALLB 101

__device__ __forceinline__ float blockReduceSum256(float v, float* sh) {
  int tid = threadIdx.x;
  sh[tid] = v;
  __syncthreads();
  for (int s = 128; s > 0; s >>= 1) {
    if (tid < s) sh[tid] += sh[tid + s];
    __syncthreads();
  }
  float r = sh[0];
  __syncthreads();
  return r;
}

__device__ __forceinline__ void ce_upd(float& m, float& s, float& sx, float4 v) {
  sx += (v.x + v.y) + (v.z + v.w);
  float lm = fmaxf(fmaxf(v.x, v.y), fmaxf(v.z, v.w));
  float nm = fmaxf(m, lm);
  s = s * __expf(m - nm) + __expf(v.x - nm) + __expf(v.y - nm) + __expf(v.z - nm) + __expf(v.w - nm);
  m = nm;
}

__global__ __launch_bounds__(256) void fused_main(
    const float* __restrict__ logits, const int* __restrict__ labels, const int* __restrict__ amask,
    const float* __restrict__ enc, const float* __restrict__ dh,
    const float* __restrict__ g_e, const float* __restrict__ be_, const float* __restrict__ W1e,
    const float* __restrict__ b1e, const float* __restrict__ W2e, const float* __restrict__ b2e,
    const float* __restrict__ g_t, const float* __restrict__ bt_, const float* __restrict__ W1t,
    const float* __restrict__ b1t, const float* __restrict__ W2t, const float* __restrict__ b2t,
    const float* __restrict__ W_bow, const float* __restrict__ b_bow,
    float* __restrict__ tok, float* __restrict__ vfs,
    float* __restrict__ ze, float* __restrict__ zt,
    float* __restrict__ bowp, float* __restrict__ divp, float* __restrict__ var_p) {
  __shared__ float smem[1792];
  int tid = threadIdx.x;
  int blk = blockIdx.x;

  if (blk >= SMALLB) {
    // ---------------- CE: one-pass online softmax, 4 independent chains, MLP=4 ----------------
    int row = blk - SMALLB;
    const float* x = logits + (size_t)row * VV;
    const float4* x4 = (const float4*)x;
    float m0 = -INFINITY, m1 = -INFINITY, m2 = -INFINITY, m3 = -INFINITY;
    float s0 = 0.f, s1 = 0.f, s2 = 0.f, s3 = 0.f, sx = 0.f;
    // 8000 float4s = 8 groups x 4 chunks x 256 threads, last chunk partial (tid<64)
#pragma unroll
    for (int g = 0; g < 8; ++g) {
      int base = (g << 10) + tid;
      float4 v0 = x4[base];
      float4 v1 = x4[base + 256];
      float4 v2 = x4[base + 512];
      ce_upd(m0, s0, sx, v0);
      ce_upd(m1, s1, sx, v1);
      ce_upd(m2, s2, sx, v2);
      if (g < 7 || tid < 64) {   // wave-uniform guard (64-lane boundary)
        float4 v3 = x4[base + 768];
        ce_upd(m3, s3, sx, v3);
      }
    }
    // merge 4 chains
    float m = fmaxf(fmaxf(m0, m1), fmaxf(m2, m3));
    float s = s0 * __expf(m0 - m) + s1 * __expf(m1 - m) + s2 * __expf(m2 - m) + s3 * __expf(m3 - m);

    float* sm_ = smem;
    float* ss_ = smem + 256;
    float* sxa = smem + 512;
    sm_[tid] = m; ss_[tid] = s; sxa[tid] = sx;
    __syncthreads();
    for (int o = 128; o > 0; o >>= 1) {
      if (tid < o) {
        float m2_ = sm_[tid + o], s2_ = ss_[tid + o];
        float nm = fmaxf(sm_[tid], m2_);
        ss_[tid] = ss_[tid] * __expf(sm_[tid] - nm) + s2_ * __expf(m2_ - nm);
        sm_[tid] = nm;
        sxa[tid] += sxa[tid + o];
      }
      __syncthreads();
    }
    if (tid == 0) {
      float M = sm_[0], L = logf(ss_[0]), SX = sxa[0];
      int lab = labels[row];
      bool valid = (lab != 0) && (lab != -100);
      int lc = lab < 0 ? 0 : (lab > VV - 1 ? VV - 1 : lab);
      float xl = x[lc];
      float lp_lab = xl - M - L;
      float lp_sum = SX - (float)VV * (M + L);
      float tl = -((1.f - EPS_LS) * lp_lab + (EPS_LS / (float)VV) * lp_sum);
      tok[row] = valid ? tl : 0.f;
      vfs[row] = valid ? 1.f : 0.f;
    }
    return;
  }

  if (blk < 32) {
    // ---------------- projection heads ----------------
    float* xs = smem;          // HH
    float* hs = smem + 768;    // PP
    float* red = smem + 1152;  // 256
    float* mf = smem + 1408;   // TT
    float* mden = smem + 1536; // 1
    bool is_t = blk >= BB;
    int b = blk & (BB - 1);
    const float *g, *bb_, *W1, *b1, *W2, *b2;
    float* zout;
    if (is_t) { g = g_t; bb_ = bt_; W1 = W1t; b1 = b1t; W2 = W2t; b2 = b2t; zout = zt; }
    else      { g = g_e; bb_ = be_; W1 = W1e; b1 = b1e; W2 = W2e; b2 = b2e; zout = ze; }

    if (is_t) {
      if (tid < TT) mf[tid] = (float)amask[b * TT + tid];
      __syncthreads();
      if (tid == 0) {
        float sum = 0.f;
        for (int t = 0; t < TT; t++) sum += mf[t];
        mden[0] = fmaxf(sum, 1.f);
      }
      __syncthreads();
      const float* dbase = dh + (size_t)b * TT * HH;
      for (int h = tid; h < HH; h += 256) {
        const float* db = dbase + h;
        float a0 = 0.f, a1 = 0.f, a2 = 0.f, a3 = 0.f;
#pragma unroll 8
        for (int t = 0; t < TT; t += 4) {
          a0 += db[(t + 0) * HH] * mf[t + 0];
          a1 += db[(t + 1) * HH] * mf[t + 1];
          a2 += db[(t + 2) * HH] * mf[t + 2];
          a3 += db[(t + 3) * HH] * mf[t + 3];
        }
        xs[h] = ((a0 + a1) + (a2 + a3)) / mden[0];
      }
    } else {
      for (int k = tid; k < HH; k += 256) xs[k] = enc[b * HH + k];
    }
    __syncthreads();

    float s1 = 0.f, s2 = 0.f;
    for (int k = tid; k < HH; k += 256) { float v = xs[k]; s1 += v; s2 += v * v; }
    s1 = blockReduceSum256(s1, red);
    s2 = blockReduceSum256(s2, red);
    float mean = s1 / (float)HH;
    float var = s2 / (float)HH - mean * mean;
    float rstd = rsqrtf(var + 1e-5f);
    for (int k = tid; k < HH; k += 256) xs[k] = (xs[k] - mean) * rstd * g[k] + bb_[k];
    __syncthreads();

    for (int j = tid; j < PP; j += 256) {
      float a0 = 0.f, a1 = 0.f;
#pragma unroll 8
      for (int k = 0; k < HH; k += 2) {
        a0 += xs[k] * W1[k * PP + j];
        a1 += xs[k + 1] * W1[(k + 1) * PP + j];
      }
      float acc = b1[j] + a0 + a1;
      hs[j] = 0.5f * acc * (1.f + erff(acc * 0.70710678118654752440f));
    }
    __syncthreads();
    for (int j = tid; j < PP; j += 256) {
      float a0 = 0.f, a1 = 0.f;
#pragma unroll 8
      for (int k = 0; k < PP; k += 2) {
        a0 += hs[k] * W2[k * PP + j];
        a1 += hs[k + 1] * W2[(k + 1) * PP + j];
      }
      xs[j] = b2[j] + a0 + a1;
    }
    __syncthreads();
    float sq = 0.f;
    for (int j = tid; j < PP; j += 256) { float v = xs[j]; sq += v * v; }
    sq = blockReduceSum256(sq, red);
    float inv = 1.f / fmaxf(sqrtf(sq), 1e-12f);
    for (int j = tid; j < PP; j += 256) zout[b * PP + j] = xs[j] * inv;
    return;
  }

  if (blk < 96) {
    // ---------------- BoW partial dot: block = (b, k-quarter), thread = (ks, iw) ----------------
    int bb = blk - 32;
    int b = bb >> 2, kq = bb & 3;
    int iw = tid & 63, ks = tid >> 6;  // 4 sub-splits of 48 k each
    const float* er = enc + b * HH;
    int k0 = kq * 192 + ks * 48;
    float acc = 0.f;
#pragma unroll 8
    for (int k = 0; k < 48; ++k) acc += er[k0 + k] * W_bow[(k0 + k) * NBOWD + iw];
    smem[ks * 64 + iw] = acc;
    __syncthreads();
    if (tid < 64) bowp[bb * 64 + tid] = smem[tid] + smem[64 + tid] + smem[128 + tid] + smem[192 + tid];
    return;
  }

  if (blk < 100) {
    // ---------------- diversity Gram partial: block = k-quarter, thread = (i,j) pair ----------------
    int kq = blk - 96;
    int i = tid >> 4, j = tid & 15;
    const float* a = enc + i * HH + kq * 192;
    const float* c = enc + j * HH + kq * 192;
    float a0 = 0.f, a1 = 0.f;
#pragma unroll 8
    for (int k = 0; k < 192; k += 2) {
      a0 += a[k] * c[k];
      a1 += a[k + 1] * c[k + 1];
    }
    divp[kq * 256 + tid] = a0 + a1;
    return;
  }

  {
    // ---------------- variance regularizer (ddof=1) ----------------
    float vsum = 0.f;
    for (int d = tid; d < HH; d += 256) {
      float a1 = 0.f, a2 = 0.f;
#pragma unroll
      for (int b = 0; b < BB; b++) { float v = enc[b * HH + d]; a1 += v; a2 += v * v; }
      float mean = a1 / (float)BB;
      float vr = (a2 - (float)BB * mean * mean) / (float)(BB - 1);
      vsum += __expf(-vr);
    }
    float r = blockReduceSum256(vsum, smem);
    if (tid == 0) var_p[0] = r / (float)HH;
  }
}

// ---------------- epilogue: assemble partials + InfoNCE + combine ----------------
__global__ __launch_bounds__(256) void finalize2(
    const float* __restrict__ tok, const float* __restrict__ vfs,
    const float* __restrict__ ze, const float* __restrict__ zt,
    const float* __restrict__ bowp, const float* __restrict__ divp, const float* __restrict__ var_p,
    const int* __restrict__ labels, const float* __restrict__ b_bow,
    float* __restrict__ out) {
  __shared__ float sh[256];
  __shared__ float smat[256];
  __shared__ float misc[40];
  __shared__ int flags[BB * NBOWD];
  int tid = threadIdx.x;

  // zero BoW target flags, then token-scatter
  for (int i = tid; i < BB * NBOWD; i += 256) flags[i] = 0;
  __syncthreads();
  for (int i = tid; i < BB * TT; i += 256) {
    int lab = labels[i];
    if (lab != 0 && lab != -100) {
      int lc = lab < 0 ? 0 : (lab > VV - 1 ? VV - 1 : lab);
      if (lc % 500 == 0) {
        int iw = lc / 500;
        if (iw < NBOWD) flags[(i >> 7) * NBOWD + iw] = 1;
      }
    }
  }

  // CE reduce
  float tsum = 0.f, csum = 0.f;
  for (int i = tid; i < BB * TT; i += 256) { tsum += tok[i]; csum += vfs[i]; }
  float ce_sum = blockReduceSum256(tsum, sh);
  float ce_cnt = blockReduceSum256(csum, sh);

  // InfoNCE
  {
    int i = tid >> 4, j = tid & 15;
    const float* a = ze + i * PP;
    const float* c = zt + j * PP;
    float a0 = 0.f, a1 = 0.f;
#pragma unroll 8
    for (int k = 0; k < PP; k += 2) { a0 += a[k] * c[k]; a1 += a[k + 1] * c[k + 1]; }
    smat[tid] = (a0 + a1) * (1.f / TAUC);
  }
  __syncthreads();
  if (tid < 32) {
    bool isrow = tid < 16;
    int r = tid & 15;
    float mx = -1e30f;
    for (int j = 0; j < 16; j++) { float v = isrow ? smat[r * 16 + j] : smat[j * 16 + r]; mx = fmaxf(mx, v); }
    float se = 0.f;
    for (int j = 0; j < 16; j++) { float v = isrow ? smat[r * 16 + j] : smat[j * 16 + r]; se += __expf(v - mx); }
    misc[tid] = smat[r * 17] - mx - logf(se);
  }
  __syncthreads();
  float align;
  if (tid == 0) {
    float li = 0.f, lj = 0.f;
    for (int r = 0; r < 16; r++) { li += misc[r]; lj += misc[16 + r]; }
    misc[33] = 0.5f * (-(li / 16.f) - (lj / 16.f));
  }
  __syncthreads();
  align = misc[33];
  __syncthreads();

  // BoW BCE from partials + flags
  float bsum = 0.f;
  for (int e = tid; e < BB * NBOWD; e += 256) {
    int b = e >> 6, iw = e & 63;
    float bl = b_bow[iw] + bowp[(b * 4 + 0) * 64 + iw] + bowp[(b * 4 + 1) * 64 + iw]
             + bowp[(b * 4 + 2) * 64 + iw] + bowp[(b * 4 + 3) * 64 + iw];
    float tgt = (float)flags[e];
    bsum += fmaxf(bl, 0.f) - bl * tgt + log1pf(__expf(-fabsf(bl)));
  }
  float bce = blockReduceSum256(bsum, sh) / (float)(BB * NBOWD);

  // diversity from Gram partials
  smat[tid] = divp[tid] + divp[256 + tid] + divp[512 + tid] + divp[768 + tid];
  __syncthreads();
  float contrib = 0.f;
  {
    int i = tid >> 4, j = tid & 15;
    if (i != j) {
      float ni = fmaxf(sqrtf(smat[i * 17]), 1e-12f);
      float nj = fmaxf(sqrtf(smat[j * 17]), 1e-12f);
      contrib = fabsf(smat[tid]) / (ni * nj);
    }
  }
  float divs = blockReduceSum256(contrib, sh) / (float)(BB * BB - BB);

  if (tid == 0) {
    float ce = ce_sum / fmaxf(ce_cnt, 1.f);
    out[0] = 1.0f * ce + 0.5f * align + 0.2f * bce + 0.1f * divs + 0.05f * var_p[0];
  }
}

extern "C" void kernel_launch(void* const* d_in, const int* in_sizes, int n_in,
                              void* d_out, int out_size, void* d_ws, size_t ws_size,
                              hipStream_t stream) {
  const float* logits = (const float*)d_in[0];
  const int* labels   = (const int*)d_in[1];
  const int* amask    = (const int*)d_in[2];
  const float* enc    = (const float*)d_in[3];
  const float* dh     = (const float*)d_in[4];
  const float* g_e    = (const float*)d_in[5];
  const float* be_    = (const float*)d_in[6];
  const float* W1e    = (const float*)d_in[7];
  const float* b1e    = (const float*)d_in[8];
  const float* W2e    = (const float*)d_in[9];
  const float* b2e    = (const float*)d_in[10];
  const float* g_t    = (const float*)d_in[11];
  const float* bt_    = (const float*)d_in[12];
  const float* W1t    = (const float*)d_in[13];
  const float* b1t    = (const float*)d_in[14];
  const float* W2t    = (const float*)d_in[15];
  const float* b2t    = (const float*)d_in[16];
  const float* W_bow  = (const float*)d_in[17];
  const float* b_bow  = (const float*)d_in[18];

  float* f     = (float*)d_ws;
  float* tok   = f;          // 2048
  float* vfs   = f + 2048;   // 2048
  float* ze    = f + 4096;   // 6144
  float* zt    = f + 10240;  // 6144
  float* bowp  = f + 16384;  // 4096
  float* divp  = f + 20480;  // 1024
  float* var_p = f + 21504;  // 1

  fused_main<<<SMALLB + BB * TT, 256, 0, stream>>>(
      logits, labels, amask, enc, dh,
      g_e, be_, W1e, b1e, W2e, b2e,
      g_t, bt_, W1t, b1t, W2t, b2t,
      W_bow, b_bow, tok, vfs, ze, zt, bowp, divp, var_p);
  finalize2<<<1, 256, 0, stream>>>(tok, vfs, ze, zt, bowp, divp, var_p, labels, b_bow, (float*)d_out);
}